// Round 8
// baseline (139.380 us; speedup 1.0000x reference)
//
#include <hip/hip_runtime.h>

#define HW 512
#define NSTATE (HW * HW)   // 262144
#define NC4_X 196608       // x as float4 (3*H*W/4)
#define NC4_POLROW 262144  // Wpol row stride in float4
#define NC4_V 65536        // v as float4

#define NWIN_MV 768   // 1024-col windows per matrix (W1 / Wpol-x)
#define NWIN_PV 1024  // 256-col windows over Wpol v-cols

// ws layout (float offsets)
#define WS_PART1 0                      // 768*32
#define WS_PARTPX 24576                 // 768*32
#define WS_PARTPV 49152                 // 1024*32
#define WS_H2 81920                     // 64
#define WS_P 81984                      // 262144
#define WS_RD (WS_P + NSTATE)
#define WS_V (WS_RD + NSTATE)

#define SGB __builtin_amdgcn_sched_group_barrier

typedef float f32x4 __attribute__((ext_vector_type(4)));
__device__ __forceinline__ float dot4v(f32x4 a, f32x4 b) {
  return a[0] * b[0] + a[1] * b[1] + a[2] * b[2] + a[3] * b[3];
}
__device__ __forceinline__ float wred(float a) {
  a += __shfl_xor(a, 32);
  a += __shfl_xor(a, 16);
  a += __shfl_xor(a, 8);
  a += __shfl_xor(a, 4);
  a += __shfl_xor(a, 2);
  a += __shfl_xor(a, 1);
  return a;
}

// ---------------------------------------------------------------------------
// K1: W1@x and Wpol[:, x-cols]@x partials, rop-shaped (the one measured-fast
// stream shape): one wave = one (matrix, 1024-col window); x-window in
// REGISTERS (4 f32x4); 16 batches of {2 rows x 4 contiguous 1KB loads} = 8
// independent loads per wait, pinned live via empty asm so regalloc cannot
// split the batch (R4/R5 failure: VGPR 20-32 -> serialized, 1.4 TB/s).
// No LDS. 384 blocks x 4 waves.
// ---------------------------------------------------------------------------
__global__ __launch_bounds__(256, 4) void mv_dual(
    const f32x4* __restrict__ W1, const f32x4* __restrict__ Wpol,
    const f32x4* __restrict__ x, float* __restrict__ part1,
    float* __restrict__ partPx) {
  int tid = threadIdx.x, wave = tid >> 6, lane = tid & 63;
  int gtask = blockIdx.x * 4 + wave;  // 0..1535
  int m = gtask >= NWIN_MV;
  int win = m ? gtask - NWIN_MV : gtask;  // 0..767
  size_t rs4 = m ? (size_t)NC4_POLROW : (size_t)NC4_X;
  const f32x4* __restrict__ wp = (m ? Wpol + NC4_V : W1) + (size_t)win * 256;
  const f32x4* __restrict__ xp = x + (size_t)win * 256;
  f32x4 xr0 = xp[lane], xr1 = xp[64 + lane], xr2 = xp[128 + lane],
        xr3 = xp[192 + lane];
  float* outp = (m ? partPx : part1) + win * 32;
#pragma unroll 1
  for (int bt = 0; bt < 16; ++bt) {
    const f32x4* p0 = wp + (size_t)(bt * 2) * rs4 + lane;
    const f32x4* p1 = wp + (size_t)(bt * 2 + 1) * rs4 + lane;
    f32x4 a0 = p0[0], a1 = p0[64], a2 = p0[128], a3 = p0[192];
    f32x4 b0 = p1[0], b1 = p1[64], b2 = p1[128], b3 = p1[192];
    asm volatile("" : "+v"(a0), "+v"(a1), "+v"(a2), "+v"(a3), "+v"(b0),
                      "+v"(b1), "+v"(b2), "+v"(b3));
    SGB(0x020, 8, 0);  // the 8-load cluster
    float pr0 = dot4v(a0, xr0) + dot4v(a1, xr1) + dot4v(a2, xr2) +
                dot4v(a3, xr3);
    float pr1 = dot4v(b0, xr0) + dot4v(b1, xr1) + dot4v(b2, xr2) +
                dot4v(b3, xr3);
    pr0 = wred(pr0);
    pr1 = wred(pr1);
    if (lane == 0) {
      outp[bt * 2] = pr0;
      outp[bt * 2 + 1] = pr1;
    }
  }
}

// ---------------------------------------------------------------------------
// K5: Wpol[:, v-cols] @ v partials, same shape. One wave = one 256-col
// window (v-window = 1 f32x4/lane in registers); 4 batches of 8 rows x 1
// load. 256 blocks x 4 waves.
// ---------------------------------------------------------------------------
__global__ __launch_bounds__(256, 4) void mv_polv(
    const f32x4* __restrict__ Wpol, const f32x4* __restrict__ v,
    float* __restrict__ partPv) {
  int tid = threadIdx.x, wave = tid >> 6, lane = tid & 63;
  int win = blockIdx.x * 4 + wave;  // 0..1023
  const f32x4* __restrict__ wp = Wpol + (size_t)win * 64;
  f32x4 xr = v[(size_t)win * 64 + lane];
  float* outp = partPv + win * 32;
#pragma unroll 1
  for (int bt = 0; bt < 4; ++bt) {
    const f32x4* p = wp + (size_t)(bt * 8) * NC4_POLROW + lane;
    f32x4 w0 = p[0 * NC4_POLROW], w1 = p[1 * NC4_POLROW];
    f32x4 w2 = p[2 * NC4_POLROW], w3 = p[3 * NC4_POLROW];
    f32x4 w4 = p[4 * NC4_POLROW], w5 = p[5 * NC4_POLROW];
    f32x4 w6 = p[6 * NC4_POLROW], w7 = p[7 * NC4_POLROW];
    asm volatile("" : "+v"(w0), "+v"(w1), "+v"(w2), "+v"(w3), "+v"(w4),
                      "+v"(w5), "+v"(w6), "+v"(w7));
    SGB(0x020, 8, 0);
    float pr[8];
    pr[0] = dot4v(w0, xr); pr[1] = dot4v(w1, xr);
    pr[2] = dot4v(w2, xr); pr[3] = dot4v(w3, xr);
    pr[4] = dot4v(w4, xr); pr[5] = dot4v(w5, xr);
    pr[6] = dot4v(w6, xr); pr[7] = dot4v(w7, xr);
#pragma unroll
    for (int j = 0; j < 8; ++j) pr[j] = wred(pr[j]);
    if (lane == 0) {
#pragma unroll
      for (int j = 0; j < 8; ++j) outp[bt * 8 + j] = pr[j];
    }
  }
}

// ---------------------------------------------------------------------------
// finish_h: reduce part1[768][32] -> h1 = relu(W1@x+b1); h2 = relu(W2@h1+b2).
// 1024 threads, 32 groups.
// ---------------------------------------------------------------------------
__global__ __launch_bounds__(1024) void finish_h(
    const float* __restrict__ partials, const float* __restrict__ b1,
    const float* __restrict__ W2, const float* __restrict__ b2,
    float* __restrict__ h2out) {
  __shared__ float red[32][32];
  __shared__ float h1[32];
  int tid = threadIdx.x;
  int row = tid & 31, grp = tid >> 5;
  float s = 0.f;
  for (int b = grp; b < NWIN_MV; b += 32) s += partials[b * 32 + row];
  red[grp][row] = s;
  __syncthreads();
  if (tid < 32) {
    float t = b1[tid];
    for (int g = 0; g < 32; ++g) t += red[g][tid];
    h1[tid] = fmaxf(t, 0.f);
  }
  __syncthreads();
  if (tid < 64) {
    float t = b2[tid];
    for (int k = 0; k < 32; ++k) t += W2[tid * 32 + k] * h1[k];
    h2out[tid] = fmaxf(t, 0.f);
  }
}

// ---------------------------------------------------------------------------
// rop: p = sig(Wp@h2+bp), rd = sig(Wri@h2+bri) - sig(Wro@h2+bro).
// Flat-span streaming (R5 version — measured fast, unchanged).
// ---------------------------------------------------------------------------
#define SPAN_ROP 1024
__global__ __launch_bounds__(256) void rop_kernel(
    const float4* __restrict__ Wro4, const float* __restrict__ bro,
    const float4* __restrict__ Wri4, const float* __restrict__ bri,
    const float4* __restrict__ Wp4, const float* __restrict__ bp,
    const float* __restrict__ h2, float* __restrict__ p_out,
    float* __restrict__ rd_out) {
  __shared__ float dots[4][3][64];
  int tid = threadIdx.x;
  int wave = tid >> 6, lane = tid & 63;
  int grp = lane >> 4;
  float4 h4 = ((const float4*)h2)[lane & 15];
  int span = blockIdx.x * 4 + wave;       // [0,4096)
  size_t base = (size_t)span * SPAN_ROP;  // first float4 of span
  const float4* mats[3] = {Wro4, Wri4, Wp4};
#pragma unroll
  for (int m = 0; m < 3; ++m) {
    const float4* __restrict__ W = mats[m] + base + lane;
#pragma unroll
    for (int batch = 0; batch < 2; ++batch) {
      float4 w[8];
#pragma unroll
      for (int j = 0; j < 8; ++j) w[j] = W[(batch * 8 + j) * 64];
      SGB(0x020, 8, 0);
      float part[8];
#pragma unroll
      for (int j = 0; j < 8; ++j)
        part[j] = w[j].x * h4.x + w[j].y * h4.y + w[j].z * h4.z + w[j].w * h4.w;
#pragma unroll
      for (int j = 0; j < 8; ++j) {
        part[j] += __shfl_xor(part[j], 8);
        part[j] += __shfl_xor(part[j], 4);
        part[j] += __shfl_xor(part[j], 2);
        part[j] += __shfl_xor(part[j], 1);
      }
      if ((lane & 15) == 0) {
#pragma unroll
        for (int j = 0; j < 8; ++j)
          dots[wave][m][(batch * 8 + j) * 4 + grp] = part[j];
      }
    }
  }
  __syncthreads();
  int o = blockIdx.x * 256 + tid;
  float dro = dots[tid >> 6][0][tid & 63] + bro[o];
  float dri = dots[tid >> 6][1][tid & 63] + bri[o];
  float dp = dots[tid >> 6][2][tid & 63] + bp[o];
  float sro = 1.f / (1.f + __expf(-dro));
  float sri = 1.f / (1.f + __expf(-dri));
  float pv = 1.f / (1.f + __expf(-dp));
  p_out[o] = pv;
  rd_out[o] = sri - sro;
}

// ---------------------------------------------------------------------------
// Value iteration, ONE launch, 1024 blocks. 16x16 tile + halo 10 in LDS,
// 10 local iterations; zero-padding semantics preserved.
// ---------------------------------------------------------------------------
#define TILE 16
#define HALO 10
#define LR 36  // TILE + 2*HALO
__global__ __launch_bounds__(256) void valiter_kernel(
    const float* __restrict__ p, const float* __restrict__ rd,
    float* __restrict__ vout) {
  __shared__ float u[LR + 2][LR + 3];
  __shared__ float pp[LR][LR + 1];
  __shared__ float rr[LR][LR + 1];
  __shared__ float vv[LR][LR + 1];
  int tid = threadIdx.x;
  int ti = blockIdx.x >> 5, tj = blockIdx.x & 31;
  int gi0 = ti * TILE - HALO, gj0 = tj * TILE - HALO;
  for (int idx = tid; idx < (LR + 2) * (LR + 3); idx += 256)
    ((float*)u)[idx] = 0.f;
  for (int idx = tid; idx < LR * LR; idx += 256) {
    int i = idx / LR, j = idx % LR;
    int gi = gi0 + i, gj = gj0 + j;
    bool ok = (gi >= 0) & (gi < HW) & (gj >= 0) & (gj < HW);
    pp[i][j] = ok ? p[gi * HW + gj] : 0.f;
    rr[i][j] = ok ? rd[gi * HW + gj] : 0.f;
    vv[i][j] = 0.f;
  }
  __syncthreads();
  for (int k = 0; k < 10; ++k) {
#pragma unroll
    for (int idx = tid; idx < LR * LR; idx += 256) {
      int i = idx / LR, j = idx % LR;
      u[i + 1][j + 1] = vv[i][j] * pp[i][j] + rr[i][j];
    }
    __syncthreads();
#pragma unroll
    for (int idx = tid; idx < LR * LR; idx += 256) {
      int i = idx / LR, j = idx % LR;
      float m = u[i][j];
      m = fmaxf(m, u[i][j + 1]);
      m = fmaxf(m, u[i][j + 2]);
      m = fmaxf(m, u[i + 1][j]);
      m = fmaxf(m, u[i + 1][j + 2]);
      m = fmaxf(m, u[i + 2][j]);
      m = fmaxf(m, u[i + 2][j + 1]);
      m = fmaxf(m, u[i + 2][j + 2]);
      vv[i][j] = m;
    }
    __syncthreads();
  }
  if (tid < TILE * TILE) {
    int a = tid >> 4, b = tid & 15;
    vout[(ti * TILE + a) * HW + tj * TILE + b] = vv[HALO + a][HALO + b];
  }
}

// ---------------------------------------------------------------------------
// finish_pol: hp = relu(bpol + sum partPx[768][32] + sum partPv[1024][32]);
// logits = Whead@hp + bhead; softmax; out[8] = v[pos]. 1024 threads.
// ---------------------------------------------------------------------------
__global__ __launch_bounds__(1024) void finish_pol(
    const float* __restrict__ partPx, const float* __restrict__ partPv,
    const float* __restrict__ bpol, const float* __restrict__ Whead,
    const float* __restrict__ bhead, const float* __restrict__ v,
    const int* __restrict__ pos, float* __restrict__ out) {
  __shared__ float red[32][32];
  __shared__ float hp[32];
  __shared__ float logits[8];
  int tid = threadIdx.x;
  int row = tid & 31, grp = tid >> 5;
  float s = 0.f;
  for (int b = grp; b < NWIN_MV; b += 32) s += partPx[b * 32 + row];
  for (int b = grp; b < NWIN_PV; b += 32) s += partPv[b * 32 + row];
  red[grp][row] = s;
  __syncthreads();
  if (tid < 32) {
    float t = bpol[tid];
    for (int g = 0; g < 32; ++g) t += red[g][tid];
    hp[tid] = fmaxf(t, 0.f);
  }
  __syncthreads();
  if (tid < 8) {
    float t = bhead[tid];
    for (int k = 0; k < 32; ++k) t += Whead[tid * 32 + k] * hp[k];
    logits[tid] = t;
  }
  __syncthreads();
  if (tid == 0) {
    float mx = logits[0];
    for (int j = 1; j < 8; ++j) mx = fmaxf(mx, logits[j]);
    float e[8], sum = 0.f;
    for (int j = 0; j < 8; ++j) {
      e[j] = __expf(logits[j] - mx);
      sum += e[j];
    }
    for (int j = 0; j < 8; ++j) out[j] = e[j] / sum;
    out[8] = v[pos[0] * HW + pos[1]];
  }
}

extern "C" void kernel_launch(void* const* d_in, const int* in_sizes, int n_in,
                              void* d_out, int out_size, void* d_ws,
                              size_t ws_size, hipStream_t stream) {
  const float* x = (const float*)d_in[0];
  const int* pos = (const int*)d_in[1];
  const float* W1 = (const float*)d_in[2];
  const float* b1 = (const float*)d_in[3];
  const float* W2 = (const float*)d_in[4];
  const float* b2 = (const float*)d_in[5];
  const float* Wro = (const float*)d_in[6];
  const float* bro = (const float*)d_in[7];
  const float* Wri = (const float*)d_in[8];
  const float* bri = (const float*)d_in[9];
  const float* Wp = (const float*)d_in[10];
  const float* bp = (const float*)d_in[11];
  const float* Wpol = (const float*)d_in[12];
  const float* bpol = (const float*)d_in[13];
  const float* Whead = (const float*)d_in[14];
  const float* bhead = (const float*)d_in[15];
  float* ws = (float*)d_ws;
  float* out = (float*)d_out;

  float* part1 = ws + WS_PART1;
  float* partPx = ws + WS_PARTPX;
  float* partPv = ws + WS_PARTPV;
  float* h2 = ws + WS_H2;
  float* pbuf = ws + WS_P;
  float* rdbuf = ws + WS_RD;
  float* vbuf = ws + WS_V;

  // K1: W1@x partials AND Wpol x-column partials (independent of v)
  mv_dual<<<384, 256, 0, stream>>>((const f32x4*)W1, (const f32x4*)Wpol,
                                   (const f32x4*)x, part1, partPx);
  // K2: h1 -> h2
  finish_h<<<1, 1024, 0, stream>>>(part1, b1, W2, b2, h2);
  // K3: p, rd
  rop_kernel<<<1024, 256, 0, stream>>>((const float4*)Wro, bro,
                                       (const float4*)Wri, bri,
                                       (const float4*)Wp, bp, h2, pbuf, rdbuf);
  // K4: 10 value-iteration steps, one launch
  valiter_kernel<<<1024, 256, 0, stream>>>(pbuf, rdbuf, vbuf);
  // K5: Wpol v-column partials
  mv_polv<<<256, 256, 0, stream>>>((const f32x4*)Wpol, (const f32x4*)vbuf,
                                   partPv);
  // K6: heads + softmax + state value
  finish_pol<<<1, 1024, 0, stream>>>(partPx, partPv, bpol, Whead, bhead, vbuf,
                                     pos, out);
}

// Round 9
// 121.094 us; speedup vs baseline: 1.1510x; 1.1510x over previous
//
#include <hip/hip_runtime.h>

#define HW 512
#define NSTATE (HW * HW)   // 262144
#define NC4_X 196608       // x as float4 (3*H*W/4)
#define NC4_POLROW 262144  // Wpol row stride in float4
#define NC4_V 65536        // v as float4

#define SEG4 1024     // float4 per segment (16 KB span)
#define NSEG_MV 192   // segments per W1 row (and per Wpol x-part row)
#define NSEG_PV 64    // segments per Wpol v-part row
#define SPAN_ROP 1024

// ws layout (float offsets)
#define WS_PART1 0                    // 192*32
#define WS_PARTPX 6144                // 192*32
#define WS_PARTPV 12288               // 64*32
#define WS_H2 14336                   // 64
#define WS_P 14400                    // 262144
#define WS_RD (WS_P + NSTATE)
#define WS_V (WS_RD + NSTATE)

#define SGB __builtin_amdgcn_sched_group_barrier

// ---------------------------------------------------------------------------
// K1: W1@x and Wpol[:, x-cols]@x partials, in the ONE shape measured fast on
// this chip (rop's): each wave streams a flat, contiguous 16 KB span of W
// lying inside a single row, as 2 batches of 8 float4 loads off one base
// pointer (immediate offsets), vector operand from LDS. A span is within one
// row, so the whole span reduces into one scalar: acc += w.x, wred at end.
// Block = (matrix, row-quad q, segment s): 4 waves = rows q*4+0..3, all
// sharing the 16 KB x-segment staged once in LDS. 3072 blocks.
// R3-R8 lesson: column-window / multi-stream shapes pinned at ~2.5 TB/s
// across six structures; rop's row-span shape is the only fast one.
// ---------------------------------------------------------------------------
__global__ __launch_bounds__(256) void mv_dual(
    const float4* __restrict__ W1, const float4* __restrict__ Wpol,
    const float4* __restrict__ x, float* __restrict__ part1,
    float* __restrict__ partPx) {
  __shared__ float4 xs[SEG4];  // 16 KB
  int b = blockIdx.x;          // [0,3072)
  int m = b >= 1536;
  if (m) b -= 1536;
  int q = b / NSEG_MV, s = b - q * NSEG_MV;  // q:0..7, s:0..191
  int tid = threadIdx.x, wave = tid >> 6, lane = tid & 63;
  const float4* __restrict__ xseg = x + (size_t)s * SEG4;
#pragma unroll
  for (int k = 0; k < 4; ++k) xs[tid + k * 256] = xseg[tid + k * 256];
  __syncthreads();
  int row = q * 4 + wave;  // 0..31
  const float4* __restrict__ wrow =
      (m ? Wpol + NC4_V + (size_t)row * NC4_POLROW
         : W1 + (size_t)row * NC4_X) +
      (size_t)s * SEG4 + lane;
  float acc = 0.f;
#pragma unroll
  for (int bt = 0; bt < 2; ++bt) {
    float4 w[8];
#pragma unroll
    for (int j = 0; j < 8; ++j) w[j] = wrow[bt * 512 + j * 64];
    SGB(0x020, 8, 0);  // the 8-load cluster (rop's shape)
    float4 xv[8];
#pragma unroll
    for (int j = 0; j < 8; ++j) xv[j] = xs[bt * 512 + j * 64 + lane];
#pragma unroll
    for (int j = 0; j < 8; ++j)
      acc += w[j].x * xv[j].x + w[j].y * xv[j].y + w[j].z * xv[j].z +
             w[j].w * xv[j].w;
  }
  acc += __shfl_xor(acc, 32);
  acc += __shfl_xor(acc, 16);
  acc += __shfl_xor(acc, 8);
  acc += __shfl_xor(acc, 4);
  acc += __shfl_xor(acc, 2);
  acc += __shfl_xor(acc, 1);
  if (lane == 0) (m ? partPx : part1)[s * 32 + row] = acc;
}

// ---------------------------------------------------------------------------
// K5: Wpol[:, v-cols] @ v partials, same row-span template. 512 blocks.
// ---------------------------------------------------------------------------
__global__ __launch_bounds__(256) void mv_polv(
    const float4* __restrict__ Wpol, const float4* __restrict__ v,
    float* __restrict__ partPv) {
  __shared__ float4 xs[SEG4];  // 16 KB
  int b = blockIdx.x;          // [0,512)
  int q = b / NSEG_PV, s = b - q * NSEG_PV;  // q:0..7, s:0..63
  int tid = threadIdx.x, wave = tid >> 6, lane = tid & 63;
  const float4* __restrict__ vseg = v + (size_t)s * SEG4;
#pragma unroll
  for (int k = 0; k < 4; ++k) xs[tid + k * 256] = vseg[tid + k * 256];
  __syncthreads();
  int row = q * 4 + wave;
  const float4* __restrict__ wrow =
      Wpol + (size_t)row * NC4_POLROW + (size_t)s * SEG4 + lane;
  float acc = 0.f;
#pragma unroll
  for (int bt = 0; bt < 2; ++bt) {
    float4 w[8];
#pragma unroll
    for (int j = 0; j < 8; ++j) w[j] = wrow[bt * 512 + j * 64];
    SGB(0x020, 8, 0);
    float4 xv[8];
#pragma unroll
    for (int j = 0; j < 8; ++j) xv[j] = xs[bt * 512 + j * 64 + lane];
#pragma unroll
    for (int j = 0; j < 8; ++j)
      acc += w[j].x * xv[j].x + w[j].y * xv[j].y + w[j].z * xv[j].z +
             w[j].w * xv[j].w;
  }
  acc += __shfl_xor(acc, 32);
  acc += __shfl_xor(acc, 16);
  acc += __shfl_xor(acc, 8);
  acc += __shfl_xor(acc, 4);
  acc += __shfl_xor(acc, 2);
  acc += __shfl_xor(acc, 1);
  if (lane == 0) partPv[s * 32 + row] = acc;
}

// ---------------------------------------------------------------------------
// finish_h: reduce part1[192][32] -> h1 = relu(W1@x+b1); h2 = relu(W2@h1+b2).
// ---------------------------------------------------------------------------
__global__ __launch_bounds__(1024) void finish_h(
    const float* __restrict__ partials, const float* __restrict__ b1,
    const float* __restrict__ W2, const float* __restrict__ b2,
    float* __restrict__ h2out) {
  __shared__ float red[32][32];
  __shared__ float h1[32];
  int tid = threadIdx.x;
  int row = tid & 31, grp = tid >> 5;
  float s = 0.f;
  for (int b = grp; b < NSEG_MV; b += 32) s += partials[b * 32 + row];
  red[grp][row] = s;
  __syncthreads();
  if (tid < 32) {
    float t = b1[tid];
    for (int g = 0; g < 32; ++g) t += red[g][tid];
    h1[tid] = fmaxf(t, 0.f);
  }
  __syncthreads();
  if (tid < 64) {
    float t = b2[tid];
    for (int k = 0; k < 32; ++k) t += W2[tid * 32 + k] * h1[k];
    h2out[tid] = fmaxf(t, 0.f);
  }
}

// ---------------------------------------------------------------------------
// rop: p = sig(Wp@h2+bp), rd = sig(Wri@h2+bri) - sig(Wro@h2+bro).
// Flat-span streaming (R5 version — measured fast, unchanged).
// ---------------------------------------------------------------------------
__global__ __launch_bounds__(256) void rop_kernel(
    const float4* __restrict__ Wro4, const float* __restrict__ bro,
    const float4* __restrict__ Wri4, const float* __restrict__ bri,
    const float4* __restrict__ Wp4, const float* __restrict__ bp,
    const float* __restrict__ h2, float* __restrict__ p_out,
    float* __restrict__ rd_out) {
  __shared__ float dots[4][3][64];
  int tid = threadIdx.x;
  int wave = tid >> 6, lane = tid & 63;
  int grp = lane >> 4;
  float4 h4 = ((const float4*)h2)[lane & 15];
  int span = blockIdx.x * 4 + wave;       // [0,4096)
  size_t base = (size_t)span * SPAN_ROP;  // first float4 of span
  const float4* mats[3] = {Wro4, Wri4, Wp4};
#pragma unroll
  for (int m = 0; m < 3; ++m) {
    const float4* __restrict__ W = mats[m] + base + lane;
#pragma unroll
    for (int batch = 0; batch < 2; ++batch) {
      float4 w[8];
#pragma unroll
      for (int j = 0; j < 8; ++j) w[j] = W[(batch * 8 + j) * 64];
      SGB(0x020, 8, 0);
      float part[8];
#pragma unroll
      for (int j = 0; j < 8; ++j)
        part[j] = w[j].x * h4.x + w[j].y * h4.y + w[j].z * h4.z + w[j].w * h4.w;
#pragma unroll
      for (int j = 0; j < 8; ++j) {
        part[j] += __shfl_xor(part[j], 8);
        part[j] += __shfl_xor(part[j], 4);
        part[j] += __shfl_xor(part[j], 2);
        part[j] += __shfl_xor(part[j], 1);
      }
      if ((lane & 15) == 0) {
#pragma unroll
        for (int j = 0; j < 8; ++j)
          dots[wave][m][(batch * 8 + j) * 4 + grp] = part[j];
      }
    }
  }
  __syncthreads();
  int o = blockIdx.x * 256 + tid;
  float dro = dots[tid >> 6][0][tid & 63] + bro[o];
  float dri = dots[tid >> 6][1][tid & 63] + bri[o];
  float dp = dots[tid >> 6][2][tid & 63] + bp[o];
  float sro = 1.f / (1.f + __expf(-dro));
  float sri = 1.f / (1.f + __expf(-dri));
  float pv = 1.f / (1.f + __expf(-dp));
  p_out[o] = pv;
  rd_out[o] = sri - sro;
}

// ---------------------------------------------------------------------------
// Value iteration, ONE launch, 1024 blocks. 16x16 tile + halo 10 in LDS,
// 10 local iterations; zero-padding semantics preserved.
// ---------------------------------------------------------------------------
#define TILE 16
#define HALO 10
#define LR 36  // TILE + 2*HALO
__global__ __launch_bounds__(256) void valiter_kernel(
    const float* __restrict__ p, const float* __restrict__ rd,
    float* __restrict__ vout) {
  __shared__ float u[LR + 2][LR + 3];
  __shared__ float pp[LR][LR + 1];
  __shared__ float rr[LR][LR + 1];
  __shared__ float vv[LR][LR + 1];
  int tid = threadIdx.x;
  int ti = blockIdx.x >> 5, tj = blockIdx.x & 31;
  int gi0 = ti * TILE - HALO, gj0 = tj * TILE - HALO;
  for (int idx = tid; idx < (LR + 2) * (LR + 3); idx += 256)
    ((float*)u)[idx] = 0.f;
  for (int idx = tid; idx < LR * LR; idx += 256) {
    int i = idx / LR, j = idx % LR;
    int gi = gi0 + i, gj = gj0 + j;
    bool ok = (gi >= 0) & (gi < HW) & (gj >= 0) & (gj < HW);
    pp[i][j] = ok ? p[gi * HW + gj] : 0.f;
    rr[i][j] = ok ? rd[gi * HW + gj] : 0.f;
    vv[i][j] = 0.f;
  }
  __syncthreads();
  for (int k = 0; k < 10; ++k) {
#pragma unroll
    for (int idx = tid; idx < LR * LR; idx += 256) {
      int i = idx / LR, j = idx % LR;
      u[i + 1][j + 1] = vv[i][j] * pp[i][j] + rr[i][j];
    }
    __syncthreads();
#pragma unroll
    for (int idx = tid; idx < LR * LR; idx += 256) {
      int i = idx / LR, j = idx % LR;
      float m = u[i][j];
      m = fmaxf(m, u[i][j + 1]);
      m = fmaxf(m, u[i][j + 2]);
      m = fmaxf(m, u[i + 1][j]);
      m = fmaxf(m, u[i + 1][j + 2]);
      m = fmaxf(m, u[i + 2][j]);
      m = fmaxf(m, u[i + 2][j + 1]);
      m = fmaxf(m, u[i + 2][j + 2]);
      vv[i][j] = m;
    }
    __syncthreads();
  }
  if (tid < TILE * TILE) {
    int a = tid >> 4, b = tid & 15;
    vout[(ti * TILE + a) * HW + tj * TILE + b] = vv[HALO + a][HALO + b];
  }
}

// ---------------------------------------------------------------------------
// finish_pol: hp = relu(bpol + sum partPx[192][32] + sum partPv[64][32]);
// logits = Whead@hp + bhead; softmax; out[8] = v[pos].
// ---------------------------------------------------------------------------
__global__ __launch_bounds__(1024) void finish_pol(
    const float* __restrict__ partPx, const float* __restrict__ partPv,
    const float* __restrict__ bpol, const float* __restrict__ Whead,
    const float* __restrict__ bhead, const float* __restrict__ v,
    const int* __restrict__ pos, float* __restrict__ out) {
  __shared__ float red[32][32];
  __shared__ float hp[32];
  __shared__ float logits[8];
  int tid = threadIdx.x;
  int row = tid & 31, grp = tid >> 5;
  float s = 0.f;
  for (int b = grp; b < NSEG_MV; b += 32) s += partPx[b * 32 + row];
  for (int b = grp; b < NSEG_PV; b += 32) s += partPv[b * 32 + row];
  red[grp][row] = s;
  __syncthreads();
  if (tid < 32) {
    float t = bpol[tid];
    for (int g = 0; g < 32; ++g) t += red[g][tid];
    hp[tid] = fmaxf(t, 0.f);
  }
  __syncthreads();
  if (tid < 8) {
    float t = bhead[tid];
    for (int k = 0; k < 32; ++k) t += Whead[tid * 32 + k] * hp[k];
    logits[tid] = t;
  }
  __syncthreads();
  if (tid == 0) {
    float mx = logits[0];
    for (int j = 1; j < 8; ++j) mx = fmaxf(mx, logits[j]);
    float e[8], sum = 0.f;
    for (int j = 0; j < 8; ++j) {
      e[j] = __expf(logits[j] - mx);
      sum += e[j];
    }
    for (int j = 0; j < 8; ++j) out[j] = e[j] / sum;
    out[8] = v[pos[0] * HW + pos[1]];
  }
}

extern "C" void kernel_launch(void* const* d_in, const int* in_sizes, int n_in,
                              void* d_out, int out_size, void* d_ws,
                              size_t ws_size, hipStream_t stream) {
  const float* x = (const float*)d_in[0];
  const int* pos = (const int*)d_in[1];
  const float* W1 = (const float*)d_in[2];
  const float* b1 = (const float*)d_in[3];
  const float* W2 = (const float*)d_in[4];
  const float* b2 = (const float*)d_in[5];
  const float* Wro = (const float*)d_in[6];
  const float* bro = (const float*)d_in[7];
  const float* Wri = (const float*)d_in[8];
  const float* bri = (const float*)d_in[9];
  const float* Wp = (const float*)d_in[10];
  const float* bp = (const float*)d_in[11];
  const float* Wpol = (const float*)d_in[12];
  const float* bpol = (const float*)d_in[13];
  const float* Whead = (const float*)d_in[14];
  const float* bhead = (const float*)d_in[15];
  float* ws = (float*)d_ws;
  float* out = (float*)d_out;

  float* part1 = ws + WS_PART1;
  float* partPx = ws + WS_PARTPX;
  float* partPv = ws + WS_PARTPV;
  float* h2 = ws + WS_H2;
  float* pbuf = ws + WS_P;
  float* rdbuf = ws + WS_RD;
  float* vbuf = ws + WS_V;

  // K1: W1@x partials AND Wpol x-column partials (independent of v)
  mv_dual<<<3072, 256, 0, stream>>>((const float4*)W1, (const float4*)Wpol,
                                    (const float4*)x, part1, partPx);
  // K2: h1 -> h2
  finish_h<<<1, 1024, 0, stream>>>(part1, b1, W2, b2, h2);
  // K3: p, rd
  rop_kernel<<<1024, 256, 0, stream>>>((const float4*)Wro, bro,
                                       (const float4*)Wri, bri,
                                       (const float4*)Wp, bp, h2, pbuf, rdbuf);
  // K4: 10 value-iteration steps, one launch
  valiter_kernel<<<1024, 256, 0, stream>>>(pbuf, rdbuf, vbuf);
  // K5: Wpol v-column partials
  mv_polv<<<512, 256, 0, stream>>>((const float4*)Wpol, (const float4*)vbuf,
                                   partPv);
  // K6: heads + softmax + state value
  finish_pol<<<1, 1024, 0, stream>>>(partPx, partPv, bpol, Whead, bhead, vbuf,
                                     pos, out);
}